// Round 2
// baseline (940.198 us; speedup 1.0000x reference)
//
#include <hip/hip_runtime.h>

#define NPTS   131072      // 32 * 64 * 64 points
#define KC     1024        // codes
#define DD     64          // embedding dim
#define HWSZ   4096        // h*w
#define CHUNK  128         // codes staged in LDS per pass
#define MARGIN 4e-5f       // fp32 gap below which we re-check with f32-grid emulation

// numpy pairwise sum, n=64 contiguous path: 8 accumulators, exact order.
// fp contract OFF: an fma would change rounding vs numpy's separate mul/add.
__device__ __forceinline__ float np_pairwise64(const float* a) {
#pragma clang fp contract(off)
    float r0 = a[0], r1 = a[1], r2 = a[2], r3 = a[3];
    float r4 = a[4], r5 = a[5], r6 = a[6], r7 = a[7];
    for (int i = 8; i < 64; i += 8) {
        r0 += a[i + 0]; r1 += a[i + 1]; r2 += a[i + 2]; r3 += a[i + 3];
        r4 += a[i + 4]; r5 += a[i + 5]; r6 += a[i + 6]; r7 += a[i + 7];
    }
    return ((r0 + r1) + (r2 + r3)) + ((r4 + r5) + (r6 + r7));
}

// ---------------- embedding norms: numpy-order f32 --------------------------
__global__ void vq_bnorm(const float* __restrict__ emb, float* __restrict__ se32) {
    int k = blockIdx.x * blockDim.x + threadIdx.x;
    if (k >= KC) return;
    const float* e = emb + k * DD;
    float sq[DD];
    {
#pragma clang fp contract(off)
        for (int d = 0; d < DD; ++d) sq[d] = e[d] * e[d];
    }
    se32[k] = np_pairwise64(sq);
}

// ---------------- bulk fp32 argmin scan, 2 points/thread --------------------
__global__ void __launch_bounds__(256, 2)
vq_scan(const float* __restrict__ in, const float* __restrict__ emb,
        const float* __restrict__ se32,
        int* __restrict__ idxArr, int* __restrict__ cnt, int* __restrict__ queue) {
    __shared__ float se[CHUNK * DD];   // 32 KB staged codes
    __shared__ float sb[CHUNK];        // staged ||e||^2 (f32)
    const int tid = threadIdx.x;
    const int n0  = blockIdx.x * 512;        // block covers 512 consecutive points
    const int b   = n0 >> 12;                // 4096 points per batch image
    const int hwA = (n0 & 4095) + tid;       // point A: n0+tid, point B: +256
    const float* inb = in + (size_t)b * DD * HWSZ;

    float4 xa[16], xb[16];
#pragma unroll
    for (int r = 0; r < 16; ++r) {
        xa[r].x = inb[(4 * r + 0) * HWSZ + hwA];
        xa[r].y = inb[(4 * r + 1) * HWSZ + hwA];
        xa[r].z = inb[(4 * r + 2) * HWSZ + hwA];
        xa[r].w = inb[(4 * r + 3) * HWSZ + hwA];
        xb[r].x = inb[(4 * r + 0) * HWSZ + hwA + 256];
        xb[r].y = inb[(4 * r + 1) * HWSZ + hwA + 256];
        xb[r].z = inb[(4 * r + 2) * HWSZ + hwA + 256];
        xb[r].w = inb[(4 * r + 3) * HWSZ + hwA + 256];
    }

    float best1a = 3.4e38f, best2a = 3.4e38f; int ia = 0;
    float best1b = 3.4e38f, best2b = 3.4e38f; int ib = 0;

    for (int ch = 0; ch < KC / CHUNK; ++ch) {
        __syncthreads();
        const float4* g4 = (const float4*)(emb + ch * CHUNK * DD);
        float4* s4 = (float4*)se;
#pragma unroll
        for (int i = 0; i < 8; ++i) s4[tid + i * 256] = g4[tid + i * 256];
        if (tid < CHUNK) sb[tid] = se32[ch * CHUNK + tid];
        __syncthreads();

        for (int c = 0; c < CHUNK; ++c) {
            const float4* row = (const float4*)(se + c * DD);  // wave-uniform broadcast
            float4 aA = {0.f, 0.f, 0.f, 0.f};
            float4 aB = {0.f, 0.f, 0.f, 0.f};
#pragma unroll
            for (int r = 0; r < 16; ++r) {
                float4 ev = row[r];
                aA.x = fmaf(ev.x, xa[r].x, aA.x);
                aA.y = fmaf(ev.y, xa[r].y, aA.y);
                aA.z = fmaf(ev.z, xa[r].z, aA.z);
                aA.w = fmaf(ev.w, xa[r].w, aA.w);
                aB.x = fmaf(ev.x, xb[r].x, aB.x);
                aB.y = fmaf(ev.y, xb[r].y, aB.y);
                aB.z = fmaf(ev.z, xb[r].z, aB.z);
                aB.w = fmaf(ev.w, xb[r].w, aB.w);
            }
            float dA = (aA.x + aA.y) + (aA.z + aA.w);
            float dB = (aB.x + aB.y) + (aB.z + aB.w);
            int k = ch * CHUNK + c;
            float tA = fmaf(-2.f, dA, sb[c]);   // ||e||^2 - 2 x.e  (||x||^2 is common)
            float tB = fmaf(-2.f, dB, sb[c]);
            best2a = fminf(best2a, fmaxf(tA, best1a));
            if (tA < best1a) { best1a = tA; ia = k; }   // strict < => first index wins
            best2b = fminf(best2b, fmaxf(tB, best1b));
            if (tB < best1b) { best1b = tB; ib = k; }
        }
    }

    const int nA = n0 + tid, nB = n0 + tid + 256;
    idxArr[nA] = ia;
    idxArr[nB] = ib;
    if (best2a - best1a < MARGIN) { int p = atomicAdd(cnt, 1); queue[p] = nA; }
    if (best2b - best1b < MARGIN) { int p = atomicAdd(cnt, 1); queue[p] = nB; }
}

// ------- refine near-ties: emulate numpy f32 dists grid, first-index argmin -
__global__ void __launch_bounds__(64)
vq_refine(const float* __restrict__ in, const float* __restrict__ emb,
          const float* __restrict__ se32,
          const int* __restrict__ queue, const int* __restrict__ cnt,
          int* __restrict__ idxArr) {
    const int lane  = threadIdx.x;
    const int total = *cnt;
    for (int q = blockIdx.x; q < total; q += gridDim.x) {
        const int n  = queue[q];
        const int b  = n >> 12, hw = n & 4095;
        const float* inb = in + (size_t)b * DD * HWSZ + hw;
        float x[DD], sq[DD];
        {
#pragma clang fp contract(off)
            for (int d = 0; d < DD; ++d) x[d]  = inb[d * HWSZ];
            for (int d = 0; d < DD; ++d) sq[d] = x[d] * x[d];
        }
        const float sx = np_pairwise64(sq);   // numpy-order ||x||^2 (f32)
        float bD = 3.4e38f; int bi = 0x7fffffff;
        for (int j = 0; j < 16; ++j) {
            int k = lane + (j << 6);          // ascending k within lane
            const float* er = emb + k * DD;
            double acc = 0.0;
#pragma unroll
            for (int d = 0; d < DD; ++d)
                acc = fma((double)x[d], (double)er[d], acc);
            float m2 = (float)(2.0 * acc);    // ~= f32 sgemm result (single rounding)
            float s1, Dv;
            {
#pragma clang fp contract(off)
                s1 = sx + se32[k];            // f32 add, numpy broadcast order
                Dv = s1 - m2;                 // f32 sub -> the reference's grid value
            }
            if (Dv < bD) { bD = Dv; bi = k; } // strict < keeps first index in lane
        }
        // wave argmin-reduce, lexicographic (value, index) -> global first index
#pragma unroll
        for (int off = 32; off > 0; off >>= 1) {
            float oD = __shfl_down(bD, off);
            int   oi = __shfl_down(bi, off);
            if (oD < bD || (oD == bD && oi < bi)) { bD = oD; bi = oi; }
        }
        if (lane == 0) idxArr[n] = bi;
    }
}

// ---------------- outputs: quantized (bchw), loss (bhwc), idx (f32) ---------
__global__ void __launch_bounds__(256)
vq_out(const float* __restrict__ in, const float* __restrict__ emb,
       const int* __restrict__ idxArr,
       float* __restrict__ outq, float* __restrict__ outl, float* __restrict__ outi) {
    __shared__ float xs[64][65];   // [c][j], +1 pad: conflict-free both ways
    __shared__ float es[64][65];   // [j][c], +1 pad
    __shared__ int   sidx[64];
    const int tid = threadIdx.x;
    const int n0  = blockIdx.x * 64;   // 64 consecutive points (same b)
    const int b   = n0 >> 12;
    const int hw0 = n0 & 4095;
    const float* inb = in + (size_t)b * DD * HWSZ;

#pragma unroll
    for (int it = 0; it < 16; ++it) {
        int f = tid + it * 256;
        int c = f >> 6, j = f & 63;
        xs[c][j] = inb[c * HWSZ + hw0 + j];     // coalesced over j
    }
    if (tid < 64) sidx[tid] = idxArr[n0 + tid];
    __syncthreads();
#pragma unroll
    for (int it = 0; it < 16; ++it) {
        int f = tid + it * 256;
        int j = f >> 6, c = f & 63;
        es[j][c] = emb[sidx[j] * DD + c];       // coalesced over c per row
    }
    __syncthreads();
#pragma unroll
    for (int it = 0; it < 16; ++it) {
        int f = tid + it * 256;
        int c = f >> 6, j = f & 63;
        float x  = xs[c][j];
        float qv = es[j][c];
        outq[(size_t)(b * DD + c) * HWSZ + hw0 + j] = x + (qv - x);
    }
#pragma unroll
    for (int it = 0; it < 16; ++it) {
        int f = tid + it * 256;
        int j = f >> 6, c = f & 63;
        float x  = xs[c][j];
        float qv = es[j][c];
        float dv = qv - x;
        float l  = dv * dv;
        outl[(size_t)(n0 + j) * DD + c] = l + 0.25f * l;
    }
    if (tid < 64) outi[n0 + tid] = (float)sidx[tid];
}

extern "C" void kernel_launch(void* const* d_in, const int* in_sizes, int n_in,
                              void* d_out, int out_size, void* d_ws, size_t ws_size,
                              hipStream_t stream) {
    const float* in  = (const float*)d_in[0];   // (32,64,64,64) bchw f32
    const float* emb = (const float*)d_in[1];   // (1024,64) f32

    float* outq = (float*)d_out;                        // 8388608
    float* outl = outq + (size_t)NPTS * DD;             // 8388608
    float* outi = outl + (size_t)NPTS * DD;             // 131072 (idx as f32)

    char*  ws     = (char*)d_ws;
    float* se32   = (float*)ws;                         // 1024 * 4
    int*   idxArr = (int*)(ws + 4096);                  // NPTS * 4
    int*   cnt    = (int*)(ws + 4096 + 4 * NPTS);
    int*   queue  = (int*)(ws + 4096 + 4 * NPTS + 256); // NPTS * 4 worst case

    hipMemsetAsync(cnt, 0, sizeof(int), stream);
    vq_bnorm<<<4, 256, 0, stream>>>(emb, se32);
    vq_scan<<<NPTS / 512, 256, 0, stream>>>(in, emb, se32, idxArr, cnt, queue);
    vq_refine<<<512, 64, 0, stream>>>(in, emb, se32, queue, cnt, idxArr);
    vq_out<<<NPTS / 64, 256, 0, stream>>>(in, emb, idxArr, outq, outl, outi);
}

// Round 3
// 350.635 us; speedup vs baseline: 2.6814x; 2.6814x over previous
//
#include <hip/hip_runtime.h>

#define NPTS   131072      // 32 * 64 * 64 points
#define KC     1024        // codes
#define DD     64          // embedding dim
#define HWSZ   4096        // h*w
#define CHUNK  128         // codes staged in LDS per pass (fallback scan)
#define MARGIN 4e-5f       // fp32 gap below which we re-check with f32-grid emulation

typedef __attribute__((ext_vector_type(8))) short short8;  // 8 bf16 = 4 VGPRs
typedef __attribute__((ext_vector_type(4))) float f32x4;   // MFMA C/D frag

__device__ __forceinline__ ushort bf16_rne(float x) {
    unsigned u = __float_as_uint(x);
    unsigned r = u + 0x7fffu + ((u >> 16) & 1u);
    return (ushort)(r >> 16);
}

// numpy pairwise sum, n=64 contiguous path: 8 accumulators, exact order.
__device__ __forceinline__ float np_pairwise64(const float* a) {
#pragma clang fp contract(off)
    float r0 = a[0], r1 = a[1], r2 = a[2], r3 = a[3];
    float r4 = a[4], r5 = a[5], r6 = a[6], r7 = a[7];
    for (int i = 8; i < 64; i += 8) {
        r0 += a[i + 0]; r1 += a[i + 1]; r2 += a[i + 2]; r3 += a[i + 3];
        r4 += a[i + 4]; r5 += a[i + 5]; r6 += a[i + 6]; r7 += a[i + 7];
    }
    return ((r0 + r1) + (r2 + r3)) + ((r4 + r5) + (r6 + r7));
}

// ---------------- E prep: numpy-order ||e||^2 + bf16 hi/lo split ------------
__global__ void vq_prep_e(const float* __restrict__ emb, float* __restrict__ se32,
                          ushort* __restrict__ Eh, ushort* __restrict__ El, int writeE) {
    int k = blockIdx.x * blockDim.x + threadIdx.x;
    if (k >= KC) return;
    const float* e = emb + k * DD;
    float sq[DD];
    {
#pragma clang fp contract(off)
        for (int d = 0; d < DD; ++d) sq[d] = e[d] * e[d];
    }
    se32[k] = np_pairwise64(sq);
    if (writeE) {
        for (int d = 0; d < DD; ++d) {
            float ev = e[d];
            ushort hb = bf16_rne(ev);
            float hf = __uint_as_float(((unsigned)hb) << 16);
            Eh[k * DD + d] = hb;
            El[k * DD + d] = bf16_rne(ev - hf);
        }
    }
}

// ---------------- X prep: bchw -> [n][64] bf16 hi/lo (LDS transpose) --------
__global__ void __launch_bounds__(256)
vq_prep_x(const float* __restrict__ in, ushort* __restrict__ Xh, ushort* __restrict__ Xl) {
    __shared__ float xs[64][65];
    const int tid = threadIdx.x;
    const int n0  = blockIdx.x * 64;
    const int b   = n0 >> 12;
    const int hw0 = n0 & 4095;
    const float* inb = in + (size_t)b * DD * HWSZ;
#pragma unroll
    for (int it = 0; it < 16; ++it) {
        int f = tid + it * 256;
        int c = f >> 6, j = f & 63;
        xs[c][j] = inb[c * HWSZ + hw0 + j];     // coalesced over j
    }
    __syncthreads();
#pragma unroll
    for (int it = 0; it < 16; ++it) {
        int f = tid + it * 256;
        int j = f >> 6, d = f & 63;
        float x  = xs[d][j];
        ushort hb = bf16_rne(x);
        float  hf = __uint_as_float(((unsigned)hb) << 16);
        Xh[(size_t)(n0 + j) * DD + d] = hb;     // coalesced over d
        Xl[(size_t)(n0 + j) * DD + d] = bf16_rne(x - hf);
    }
}

// ---------------- MFMA bulk scan: 32 points x 1024 codes per wave -----------
// A[m][k]: m=lane&15, k=(lane>>4)*8+j ; B[k][n]: k=(lane>>4)*8+j, n=lane&15
// C/D:     col(n)=lane&15, row(m)=(lane>>4)*4+reg
__global__ void __launch_bounds__(256)
vq_scan_mfma(const ushort* __restrict__ Xh, const ushort* __restrict__ Xl,
             const ushort* __restrict__ Eh, const ushort* __restrict__ El,
             const float* __restrict__ se32,
             int* __restrict__ idxArr, int* __restrict__ cnt, int* __restrict__ queue) {
    const int lane = threadIdx.x & 63;
    const int wave = threadIdx.x >> 6;
    const int quad = lane >> 4;        // 0..3
    const int col  = lane & 15;        // 0..15
    const int n0w  = blockIdx.x * 128 + wave * 32;

    // A fragments: [pointsub][khalf][hi/lo], loaded once, reused for all codes
    short8 A[2][2][2];
#pragma unroll
    for (int p = 0; p < 2; ++p)
#pragma unroll
        for (int h = 0; h < 2; ++h) {
            size_t off = (size_t)(n0w + p * 16 + col) * DD + h * 32 + quad * 8;
            A[p][h][0] = *(const short8*)(Xh + off);
            A[p][h][1] = *(const short8*)(Xl + off);
        }

    float best1[8], best2[8]; int bidx[8];   // slot = psub*4 + reg
#pragma unroll
    for (int s = 0; s < 8; ++s) { best1[s] = 3.4e38f; best2[s] = 3.4e38f; bidx[s] = 0; }

    for (int cb = 0; cb < KC; cb += 64) {
        // B fragments for 4 code subtiles (L1/L2-hot: E is only 256 KB)
        short8 B[4][2][2];
        float  seb[4];
#pragma unroll
        for (int s = 0; s < 4; ++s) {
            int code = cb + s * 16 + col;
            seb[s] = se32[code];
#pragma unroll
            for (int h = 0; h < 2; ++h) {
                size_t off = (size_t)code * DD + h * 32 + quad * 8;
                B[s][h][0] = *(const short8*)(Eh + off);
                B[s][h][1] = *(const short8*)(El + off);
            }
        }
        f32x4 acc[2][4];
#pragma unroll
        for (int p = 0; p < 2; ++p)
#pragma unroll
            for (int s = 0; s < 4; ++s) acc[p][s] = (f32x4){0.f, 0.f, 0.f, 0.f};
#pragma unroll
        for (int p = 0; p < 2; ++p)
#pragma unroll
            for (int s = 0; s < 4; ++s) {
                acc[p][s] = __builtin_amdgcn_mfma_f32_16x16x32_bf16(A[p][0][0], B[s][0][0], acc[p][s], 0, 0, 0);
                acc[p][s] = __builtin_amdgcn_mfma_f32_16x16x32_bf16(A[p][1][0], B[s][1][0], acc[p][s], 0, 0, 0);
                acc[p][s] = __builtin_amdgcn_mfma_f32_16x16x32_bf16(A[p][0][0], B[s][0][1], acc[p][s], 0, 0, 0);
                acc[p][s] = __builtin_amdgcn_mfma_f32_16x16x32_bf16(A[p][1][0], B[s][1][1], acc[p][s], 0, 0, 0);
                acc[p][s] = __builtin_amdgcn_mfma_f32_16x16x32_bf16(A[p][0][1], B[s][0][0], acc[p][s], 0, 0, 0);
                acc[p][s] = __builtin_amdgcn_mfma_f32_16x16x32_bf16(A[p][1][1], B[s][1][0], acc[p][s], 0, 0, 0);
            }
        // fold: score = ||e||^2 - 2 x.e ; track best + runner-up per point-row
#pragma unroll
        for (int s = 0; s < 4; ++s) {
            int kc = cb + s * 16 + col;
#pragma unroll
            for (int p = 0; p < 2; ++p)
#pragma unroll
                for (int r = 0; r < 4; ++r) {
                    float t = fmaf(-2.f, acc[p][s][r], seb[s]);
                    int slot = p * 4 + r;
                    best2[slot] = fminf(best2[slot], fmaxf(t, best1[slot]));
                    bool lt = t < best1[slot];      // strict < => first index wins
                    best1[slot] = lt ? t : best1[slot];
                    bidx[slot]  = lt ? kc : bidx[slot];
                }
        }
    }

    // merge across the 16 columns of each quad-row (xor butterfly, 16-lane groups)
#pragma unroll
    for (int off = 1; off < 16; off <<= 1) {
#pragma unroll
        for (int s = 0; s < 8; ++s) {
            float o1 = __shfl_xor(best1[s], off);
            float o2 = __shfl_xor(best2[s], off);
            int   oi = __shfl_xor(bidx[s], off);
            float m2 = fminf(fmaxf(best1[s], o1), fminf(best2[s], o2));
            bool take = (o1 < best1[s]) || (o1 == best1[s] && oi < bidx[s]);
            best1[s] = take ? o1 : best1[s];
            bidx[s]  = take ? oi : bidx[s];
            best2[s] = m2;
        }
    }
    // lanes col 0..7 each write one point of this quad-row group
#pragma unroll
    for (int s = 0; s < 8; ++s) {
        if (col == s) {
            int n = n0w + (s >> 2) * 16 + quad * 4 + (s & 3);
            idxArr[n] = bidx[s];
            if (best2[s] - best1[s] < MARGIN) { int pos = atomicAdd(cnt, 1); queue[pos] = n; }
        }
    }
}

// ---------------- fallback bulk fp32 scan (R2), if ws too small -------------
__global__ void __launch_bounds__(256, 2)
vq_scan(const float* __restrict__ in, const float* __restrict__ emb,
        const float* __restrict__ se32,
        int* __restrict__ idxArr, int* __restrict__ cnt, int* __restrict__ queue) {
    __shared__ float se[CHUNK * DD];
    __shared__ float sb[CHUNK];
    const int tid = threadIdx.x;
    const int n0  = blockIdx.x * 512;
    const int b   = n0 >> 12;
    const int hwA = (n0 & 4095) + tid;
    const float* inb = in + (size_t)b * DD * HWSZ;
    float4 xa[16], xb[16];
#pragma unroll
    for (int r = 0; r < 16; ++r) {
        xa[r].x = inb[(4 * r + 0) * HWSZ + hwA];
        xa[r].y = inb[(4 * r + 1) * HWSZ + hwA];
        xa[r].z = inb[(4 * r + 2) * HWSZ + hwA];
        xa[r].w = inb[(4 * r + 3) * HWSZ + hwA];
        xb[r].x = inb[(4 * r + 0) * HWSZ + hwA + 256];
        xb[r].y = inb[(4 * r + 1) * HWSZ + hwA + 256];
        xb[r].z = inb[(4 * r + 2) * HWSZ + hwA + 256];
        xb[r].w = inb[(4 * r + 3) * HWSZ + hwA + 256];
    }
    float best1a = 3.4e38f, best2a = 3.4e38f; int ia = 0;
    float best1b = 3.4e38f, best2b = 3.4e38f; int ib = 0;
    for (int ch = 0; ch < KC / CHUNK; ++ch) {
        __syncthreads();
        const float4* g4 = (const float4*)(emb + ch * CHUNK * DD);
        float4* s4 = (float4*)se;
#pragma unroll
        for (int i = 0; i < 8; ++i) s4[tid + i * 256] = g4[tid + i * 256];
        if (tid < CHUNK) sb[tid] = se32[ch * CHUNK + tid];
        __syncthreads();
        for (int c = 0; c < CHUNK; ++c) {
            const float4* row = (const float4*)(se + c * DD);
            float4 aA = {0.f, 0.f, 0.f, 0.f};
            float4 aB = {0.f, 0.f, 0.f, 0.f};
#pragma unroll
            for (int r = 0; r < 16; ++r) {
                float4 ev = row[r];
                aA.x = fmaf(ev.x, xa[r].x, aA.x); aA.y = fmaf(ev.y, xa[r].y, aA.y);
                aA.z = fmaf(ev.z, xa[r].z, aA.z); aA.w = fmaf(ev.w, xa[r].w, aA.w);
                aB.x = fmaf(ev.x, xb[r].x, aB.x); aB.y = fmaf(ev.y, xb[r].y, aB.y);
                aB.z = fmaf(ev.z, xb[r].z, aB.z); aB.w = fmaf(ev.w, xb[r].w, aB.w);
            }
            float dA = (aA.x + aA.y) + (aA.z + aA.w);
            float dB = (aB.x + aB.y) + (aB.z + aB.w);
            int k = ch * CHUNK + c;
            float tA = fmaf(-2.f, dA, sb[c]);
            float tB = fmaf(-2.f, dB, sb[c]);
            best2a = fminf(best2a, fmaxf(tA, best1a));
            if (tA < best1a) { best1a = tA; ia = k; }
            best2b = fminf(best2b, fmaxf(tB, best1b));
            if (tB < best1b) { best1b = tB; ib = k; }
        }
    }
    const int nA = n0 + tid, nB = n0 + tid + 256;
    idxArr[nA] = ia;
    idxArr[nB] = ib;
    if (best2a - best1a < MARGIN) { int p = atomicAdd(cnt, 1); queue[p] = nA; }
    if (best2b - best1b < MARGIN) { int p = atomicAdd(cnt, 1); queue[p] = nB; }
}

// ------- refine near-ties: emulate numpy f32 dists grid, first-index argmin -
__global__ void __launch_bounds__(64)
vq_refine(const float* __restrict__ in, const float* __restrict__ emb,
          const float* __restrict__ se32,
          const int* __restrict__ queue, const int* __restrict__ cnt,
          int* __restrict__ idxArr) {
    const int lane  = threadIdx.x;
    const int total = *cnt;
    for (int q = blockIdx.x; q < total; q += gridDim.x) {
        const int n  = queue[q];
        const int b  = n >> 12, hw = n & 4095;
        const float* inb = in + (size_t)b * DD * HWSZ + hw;
        float x[DD], sq[DD];
        {
#pragma clang fp contract(off)
            for (int d = 0; d < DD; ++d) x[d]  = inb[d * HWSZ];
            for (int d = 0; d < DD; ++d) sq[d] = x[d] * x[d];
        }
        const float sx = np_pairwise64(sq);
        float bD = 3.4e38f; int bi = 0x7fffffff;
        for (int j = 0; j < 16; ++j) {
            int k = lane + (j << 6);
            const float* er = emb + k * DD;
            double acc = 0.0;
#pragma unroll
            for (int d = 0; d < DD; ++d)
                acc = fma((double)x[d], (double)er[d], acc);
            float m2 = (float)(2.0 * acc);
            float s1, Dv;
            {
#pragma clang fp contract(off)
                s1 = sx + se32[k];
                Dv = s1 - m2;
            }
            if (Dv < bD) { bD = Dv; bi = k; }
        }
#pragma unroll
        for (int off = 32; off > 0; off >>= 1) {
            float oD = __shfl_down(bD, off);
            int   oi = __shfl_down(bi, off);
            if (oD < bD || (oD == bD && oi < bi)) { bD = oD; bi = oi; }
        }
        if (lane == 0) idxArr[n] = bi;
    }
}

// ---------------- outputs: quantized (bchw), loss (bhwc), idx (f32) ---------
__global__ void __launch_bounds__(256)
vq_out(const float* __restrict__ in, const float* __restrict__ emb,
       const int* __restrict__ idxArr,
       float* __restrict__ outq, float* __restrict__ outl, float* __restrict__ outi) {
    __shared__ float xs[64][65];
    __shared__ float es[64][65];
    __shared__ int   sidx[64];
    const int tid = threadIdx.x;
    const int n0  = blockIdx.x * 64;
    const int b   = n0 >> 12;
    const int hw0 = n0 & 4095;
    const float* inb = in + (size_t)b * DD * HWSZ;
#pragma unroll
    for (int it = 0; it < 16; ++it) {
        int f = tid + it * 256;
        int c = f >> 6, j = f & 63;
        xs[c][j] = inb[c * HWSZ + hw0 + j];
    }
    if (tid < 64) sidx[tid] = idxArr[n0 + tid];
    __syncthreads();
#pragma unroll
    for (int it = 0; it < 16; ++it) {
        int f = tid + it * 256;
        int j = f >> 6, c = f & 63;
        es[j][c] = emb[sidx[j] * DD + c];
    }
    __syncthreads();
#pragma unroll
    for (int it = 0; it < 16; ++it) {
        int f = tid + it * 256;
        int c = f >> 6, j = f & 63;
        float x  = xs[c][j];
        float qv = es[j][c];
        outq[(size_t)(b * DD + c) * HWSZ + hw0 + j] = x + (qv - x);
    }
#pragma unroll
    for (int it = 0; it < 16; ++it) {
        int f = tid + it * 256;
        int j = f >> 6, c = f & 63;
        float x  = xs[c][j];
        float qv = es[j][c];
        float dv = qv - x;
        float l  = dv * dv;
        outl[(size_t)(n0 + j) * DD + c] = l + 0.25f * l;
    }
    if (tid < 64) outi[n0 + tid] = (float)sidx[tid];
}

extern "C" void kernel_launch(void* const* d_in, const int* in_sizes, int n_in,
                              void* d_out, int out_size, void* d_ws, size_t ws_size,
                              hipStream_t stream) {
    const float* in  = (const float*)d_in[0];   // (32,64,64,64) bchw f32
    const float* emb = (const float*)d_in[1];   // (1024,64) f32

    float* outq = (float*)d_out;
    float* outl = outq + (size_t)NPTS * DD;
    float* outi = outl + (size_t)NPTS * DD;

    char* ws = (char*)d_ws;

    // MFMA-path layout (all 16B-aligned): ~33.3 MB
    const size_t oSe  = 0;                       // f32[1024]
    const size_t oEh  = 4096;                    // u16[1024*64]
    const size_t oEl  = oEh + 131072;
    const size_t oXh  = oEl + 131072;            // u16[NPTS*64] = 16 MB
    const size_t oXl  = oXh + (size_t)NPTS * DD * 2;
    const size_t oIdx = oXl + (size_t)NPTS * DD * 2;
    const size_t oCnt = oIdx + (size_t)NPTS * 4;
    const size_t oQue = oCnt + 256;
    const size_t need = oQue + (size_t)NPTS * 4;

    if (ws_size >= need) {
        float*  se32   = (float*)(ws + oSe);
        ushort* Eh     = (ushort*)(ws + oEh);
        ushort* El     = (ushort*)(ws + oEl);
        ushort* Xh     = (ushort*)(ws + oXh);
        ushort* Xl     = (ushort*)(ws + oXl);
        int*    idxArr = (int*)(ws + oIdx);
        int*    cnt    = (int*)(ws + oCnt);
        int*    queue  = (int*)(ws + oQue);

        hipMemsetAsync(cnt, 0, sizeof(int), stream);
        vq_prep_e<<<4, 256, 0, stream>>>(emb, se32, Eh, El, 1);
        vq_prep_x<<<NPTS / 64, 256, 0, stream>>>(in, Xh, Xl);
        vq_scan_mfma<<<NPTS / 128, 256, 0, stream>>>(Xh, Xl, Eh, El, se32, idxArr, cnt, queue);
        vq_refine<<<512, 64, 0, stream>>>(in, emb, se32, queue, cnt, idxArr);
        vq_out<<<NPTS / 64, 256, 0, stream>>>(in, emb, idxArr, outq, outl, outi);
    } else {
        // fallback: R2 layout (~1.6 MB)
        float* se32   = (float*)ws;
        int*   idxArr = (int*)(ws + 4096);
        int*   cnt    = (int*)(ws + 4096 + 4 * NPTS);
        int*   queue  = (int*)(ws + 4096 + 4 * NPTS + 256);

        hipMemsetAsync(cnt, 0, sizeof(int), stream);
        vq_prep_e<<<4, 256, 0, stream>>>(emb, se32, (ushort*)0, (ushort*)0, 0);
        vq_scan<<<NPTS / 512, 256, 0, stream>>>(in, emb, se32, idxArr, cnt, queue);
        vq_refine<<<512, 64, 0, stream>>>(in, emb, se32, queue, cnt, idxArr);
        vq_out<<<NPTS / 64, 256, 0, stream>>>(in, emb, idxArr, outq, outl, outi);
    }
}

// Round 4
// 268.693 us; speedup vs baseline: 3.4991x; 1.3050x over previous
//
#include <hip/hip_runtime.h>

#define NPTS    131072     // 32 * 64 * 64 points
#define KC      1024       // codes
#define DD      64         // embedding dim
#define HWSZ    4096       // h*w
#define MARGINF 6e-5f      // packed-domain gap below which we refine on the f32 grid

typedef __attribute__((ext_vector_type(8))) short short8;  // 8 bf16 = 4 VGPRs
typedef __attribute__((ext_vector_type(4))) float f32x4;   // MFMA C/D frag

__device__ __forceinline__ ushort bf16_rne(float x) {
    unsigned u = __float_as_uint(x);
    unsigned r = u + 0x7fffu + ((u >> 16) & 1u);
    return (ushort)(r >> 16);
}

// numpy pairwise sum, n=64 contiguous path: 8 accumulators, exact order.
__device__ __forceinline__ float np_pairwise64(const float* a) {
#pragma clang fp contract(off)
    float r0 = a[0], r1 = a[1], r2 = a[2], r3 = a[3];
    float r4 = a[4], r5 = a[5], r6 = a[6], r7 = a[7];
    for (int i = 8; i < 64; i += 8) {
        r0 += a[i + 0]; r1 += a[i + 1]; r2 += a[i + 2]; r3 += a[i + 3];
        r4 += a[i + 4]; r5 += a[i + 5]; r6 += a[i + 6]; r7 += a[i + 7];
    }
    return ((r0 + r1) + (r2 + r3)) + ((r4 + r5) + (r6 + r7));
}

// ---- E prep: numpy-order ||e||^2, biased copy, MFMA-fragment-ordered bf16 --
// Ebuf block for (tile,kh,hl) holds 64 lanes x 8 shorts contiguous:
// element = E[tile*16 + (lane&15)][kh*32 + (lane>>4)*8 + j]
__global__ void vq_prep_e(const float* __restrict__ emb, float* __restrict__ se32,
                          float* __restrict__ sebB, ushort* __restrict__ Ebuf) {
    int k = blockIdx.x * blockDim.x + threadIdx.x;
    if (k >= KC) return;
    const float* e = emb + k * DD;
    float sq[DD];
    {
#pragma clang fp contract(off)
        for (int d = 0; d < DD; ++d) sq[d] = e[d] * e[d];
    }
    float s = np_pairwise64(sq);
    se32[k] = s;
    sebB[k] = s + 0.5f;                 // bias keeps scan scores strictly positive
    const int tile = k >> 4, colk = k & 15;
    for (int d = 0; d < DD; ++d) {
        int kh = d >> 5, quad = (d & 31) >> 3, jj = d & 7;
        float ev = e[d];
        ushort hb = bf16_rne(ev);
        float  hf = __uint_as_float(((unsigned)hb) << 16);
        ushort lb = bf16_rne(ev - hf);
        int pos = (quad * 16 + colk) * 8 + jj;
        Ebuf[((tile * 2 + kh) * 2 + 0) * 512 + pos] = hb;
        Ebuf[((tile * 2 + kh) * 2 + 1) * 512 + pos] = lb;
    }
}

// ---- fused: stage x -> A frags -> MFMA scan (packed-uint argmin) -> outputs
__global__ void __launch_bounds__(256)
vq_main(const float* __restrict__ in, const float* __restrict__ emb,
        const ushort* __restrict__ Ebuf, const float* __restrict__ sebB,
        float* __restrict__ outq, float* __restrict__ outl, float* __restrict__ outi,
        int* __restrict__ cnt, int* __restrict__ queue) {
    __shared__ float xs[64][129];   // [c][j], pad -> conflict-light both ways (33 KB)
    __shared__ int   sidx[128];
    const int tid = threadIdx.x;
    const int n0  = blockIdx.x * 128;     // 128 consecutive points, single batch image
    const int b   = n0 >> 12;
    const int hw0 = n0 & 4095;
    const float* inb = in + (size_t)b * DD * HWSZ;

    // stage exact x for the block's 128 points (coalesced over hw)
#pragma unroll
    for (int it = 0; it < 32; ++it) {
        int f = tid + it * 256;
        int c = f >> 7, j = f & 127;
        xs[c][j] = inb[c * HWSZ + hw0 + j];
    }
    __syncthreads();

    const int lane = tid & 63, wave = tid >> 6;
    const int quad = lane >> 4, col = lane & 15;

    // A fragments (bf16 hi/lo) straight from LDS — no global X roundtrip
    short8 A[2][2][2];   // [psub][khalf][hi/lo]
#pragma unroll
    for (int p = 0; p < 2; ++p) {
        int pt = wave * 32 + p * 16 + col;
#pragma unroll
        for (int kh = 0; kh < 2; ++kh) {
            short8 ah, al;
#pragma unroll
            for (int j = 0; j < 8; ++j) {
                float xv = xs[kh * 32 + quad * 8 + j][pt];
                ushort hb = bf16_rne(xv);
                float  hf = __uint_as_float(((unsigned)hb) << 16);
                ah[j] = (short)hb;
                al[j] = (short)bf16_rne(xv - hf);
            }
            A[p][kh][0] = ah; A[p][kh][1] = al;
        }
    }

    unsigned b1[8], b2[8];          // packed: (score+0.5 bits & ~63) | tile
#pragma unroll
    for (int s = 0; s < 8; ++s) { b1[s] = 0xFFFFFFFFu; b2[s] = 0xFFFFFFFFu; }

    for (int g = 0; g < 16; ++g) {            // 64 codes per iteration
        short8 B[4][2][2];
        float  sB[4];
#pragma unroll
        for (int s = 0; s < 4; ++s) {
            int tile = g * 4 + s;
            sB[s] = sebB[tile * 16 + col];
#pragma unroll
            for (int kh = 0; kh < 2; ++kh)
#pragma unroll
                for (int hl = 0; hl < 2; ++hl)
                    B[s][kh][hl] = *(const short8*)(Ebuf + ((tile * 2 + kh) * 2 + hl) * 512 + lane * 8);
        }
        f32x4 acc[2][4];
#pragma unroll
        for (int p = 0; p < 2; ++p)
#pragma unroll
            for (int s = 0; s < 4; ++s) acc[p][s] = (f32x4){0.f, 0.f, 0.f, 0.f};
#pragma unroll
        for (int p = 0; p < 2; ++p)
#pragma unroll
            for (int s = 0; s < 4; ++s) {
                acc[p][s] = __builtin_amdgcn_mfma_f32_16x16x32_bf16(A[p][0][0], B[s][0][0], acc[p][s], 0, 0, 0);
                acc[p][s] = __builtin_amdgcn_mfma_f32_16x16x32_bf16(A[p][1][0], B[s][1][0], acc[p][s], 0, 0, 0);
                acc[p][s] = __builtin_amdgcn_mfma_f32_16x16x32_bf16(A[p][0][0], B[s][0][1], acc[p][s], 0, 0, 0);
                acc[p][s] = __builtin_amdgcn_mfma_f32_16x16x32_bf16(A[p][1][0], B[s][1][1], acc[p][s], 0, 0, 0);
                acc[p][s] = __builtin_amdgcn_mfma_f32_16x16x32_bf16(A[p][0][1], B[s][0][0], acc[p][s], 0, 0, 0);
                acc[p][s] = __builtin_amdgcn_mfma_f32_16x16x32_bf16(A[p][1][1], B[s][1][0], acc[p][s], 0, 0, 0);
            }
        // packed-uint fold: 4 codes per slot via sorted-2-of-4 insertion
#pragma unroll
        for (int p = 0; p < 2; ++p)
#pragma unroll
            for (int r = 0; r < 4; ++r) {
                unsigned q[4];
#pragma unroll
                for (int s = 0; s < 4; ++s) {
                    float t = fmaf(-2.f, acc[p][s][r], sB[s]);       // 0.5 + se - 2x.e > 0
                    q[s] = (__float_as_uint(t) & 0xFFFFFFC0u) | (unsigned)(g * 4 + s);
                }
                unsigned a  = min(q[0], q[1]), bb = max(q[0], q[1]);
                unsigned c2 = min(q[2], q[3]), d2 = max(q[2], q[3]);
                unsigned lo = min(a, c2), hi = max(a, c2);
                unsigned sec = min(min(bb, d2), hi);                  // 2nd smallest of 4
                int sl = p * 4 + r;
                b2[sl] = min(min(b2[sl], sec), max(b1[sl], lo));
                b1[sl] = min(b1[sl], lo);
            }
    }

    // decode + 16-col butterfly merge (first-index tie-break)
    unsigned v1[8], v2[8]; int ci[8];
#pragma unroll
    for (int s = 0; s < 8; ++s) {
        ci[s] = (int)(b1[s] & 63u) * 16 + col;
        v1[s] = b1[s] & 0xFFFFFFC0u;
        v2[s] = b2[s] & 0xFFFFFFC0u;
    }
#pragma unroll
    for (int off = 1; off < 16; off <<= 1) {
#pragma unroll
        for (int s = 0; s < 8; ++s) {
            unsigned o1 = (unsigned)__shfl_xor((int)v1[s], off);
            unsigned o2 = (unsigned)__shfl_xor((int)v2[s], off);
            int      oi = __shfl_xor(ci[s], off);
            unsigned nb2 = min(min(v2[s], o2), max(v1[s], o1));
            bool take = (o1 < v1[s]) || (o1 == v1[s] && oi < ci[s]);
            v1[s] = take ? o1 : v1[s];
            ci[s] = take ? oi : ci[s];
            v2[s] = nb2;
        }
    }
#pragma unroll
    for (int s = 0; s < 8; ++s) {
        if (col == s) {
            int jloc = wave * 32 + (s >> 2) * 16 + quad * 4 + (s & 3);
            sidx[jloc] = ci[s];
            float f1 = __uint_as_float(v1[s]), f2 = __uint_as_float(v2[s]);
            if (f2 - f1 < MARGINF) { int pos = atomicAdd(cnt, 1); queue[pos] = n0 + jloc; }
        }
    }
    __syncthreads();

    // fused output epilogue: lane -> channel, loop over this wave's 32 points
    for (int t = 0; t < 32; ++t) {
        int jloc = wave * 32 + t;
        int kidx = sidx[jloc];
        float qv = emb[kidx * DD + lane];              // coalesced 256B row, L2-hot
        float x  = xs[lane][jloc];
        float dv = qv - x;
        float l  = dv * dv;
        outl[(size_t)(n0 + jloc) * DD + lane] = fmaf(0.25f, l, l);   // coalesced
        outq[((size_t)(b * DD) + lane) * HWSZ + hw0 + jloc] = x + (qv - x);  // L2-merged scatter
    }
    if (lane < 32) outi[n0 + wave * 32 + lane] = (float)sidx[wave * 32 + lane];
}

// ---- fix: emulate numpy f32 dists grid for queued points, rewrite if changed
__global__ void __launch_bounds__(256)
vq_fix(const float* __restrict__ in, const float* __restrict__ emb,
       const float* __restrict__ se32,
       const int* __restrict__ queue, const int* __restrict__ cnt,
       float* __restrict__ outq, float* __restrict__ outl, float* __restrict__ outi) {
    const int lane = threadIdx.x & 63;
    const int gw   = blockIdx.x * 4 + (threadIdx.x >> 6);
    const int nwav = gridDim.x * 4;
    const int total = *cnt;
    for (int qi = gw; qi < total; qi += nwav) {
        const int n  = queue[qi];
        const int b  = n >> 12, hw = n & 4095;
        const float* inb = in + (size_t)b * DD * HWSZ + hw;
        float x[DD], sq[DD];
        {
#pragma clang fp contract(off)
            for (int d = 0; d < DD; ++d) x[d]  = inb[d * HWSZ];
            for (int d = 0; d < DD; ++d) sq[d] = x[d] * x[d];
        }
        const float sx = np_pairwise64(sq);   // numpy-order ||x||^2 (f32)
        float bD = 3.4e38f; int bi = 0x7fffffff;
        for (int j = 0; j < 16; ++j) {
            int k = lane + (j << 6);          // ascending k within lane
            const float* er = emb + k * DD;
            double acc = 0.0;
#pragma unroll
            for (int d = 0; d < DD; ++d)
                acc = fma((double)x[d], (double)er[d], acc);
            float m2 = (float)(2.0 * acc);    // ~= f32 sgemm result (single rounding)
            float s1, Dv;
            {
#pragma clang fp contract(off)
                s1 = sx + se32[k];
                Dv = s1 - m2;                 // the reference's f32 grid value
            }
            if (Dv < bD) { bD = Dv; bi = k; }
        }
#pragma unroll
        for (int off = 32; off > 0; off >>= 1) {
            float oD = __shfl_down(bD, off);
            int   oi = __shfl_down(bi, off);
            if (oD < bD || (oD == bD && oi < bi)) { bD = oD; bi = oi; }
        }
        bi = __shfl(bi, 0);                   // broadcast winner to all lanes
        int old = (int)outi[n];
        if (bi != old) {
            float xv = in[((size_t)b * DD + lane) * HWSZ + hw];
            float qv = emb[bi * DD + lane];
            float dv = qv - xv;
            float l  = dv * dv;
            outl[(size_t)n * DD + lane] = fmaf(0.25f, l, l);
            outq[((size_t)b * DD + lane) * HWSZ + hw] = xv + (qv - xv);
            if (lane == 0) outi[n] = (float)bi;
        }
    }
}

extern "C" void kernel_launch(void* const* d_in, const int* in_sizes, int n_in,
                              void* d_out, int out_size, void* d_ws, size_t ws_size,
                              hipStream_t stream) {
    const float* in  = (const float*)d_in[0];   // (32,64,64,64) bchw f32
    const float* emb = (const float*)d_in[1];   // (1024,64) f32

    float* outq = (float*)d_out;                        // 8388608
    float* outl = outq + (size_t)NPTS * DD;             // 8388608
    float* outi = outl + (size_t)NPTS * DD;             // 131072 (idx as f32)

    char*   ws    = (char*)d_ws;                        // ~0.8 MB used
    float*  se32  = (float*)ws;                         // 4 KB
    float*  sebB  = (float*)(ws + 4096);                // 4 KB
    ushort* Ebuf  = (ushort*)(ws + 8192);               // 256 KB (frag-ordered hi/lo)
    int*    cnt   = (int*)(ws + 8192 + 262144);
    int*    queue = (int*)(ws + 8192 + 262144 + 256);   // NPTS*4 worst case

    hipMemsetAsync(cnt, 0, sizeof(int), stream);
    vq_prep_e<<<4, 256, 0, stream>>>(emb, se32, sebB, Ebuf);
    vq_main<<<NPTS / 128, 256, 0, stream>>>(in, emb, Ebuf, sebB, outq, outl, outi, cnt, queue);
    vq_fix<<<512, 256, 0, stream>>>(in, emb, se32, queue, cnt, outq, outl, outi);
}